// Round 9
// baseline (113.822 us; speedup 1.0000x reference)
//
#include <hip/hip_runtime.h>
#include <math.h>

#define PLANES   8192   // 16 batches * 512 channels
#define PLANE_SZ 4096   // 64*64
#define CHANS    512
#define NBLK     1024   // 4 blocks/CU * 256 CUs -> co-resident (proven R5-R7)
#define PPB      8      // planes (channels) per block; 64 blocks per batch
#define NBATCH   16

typedef float f32x4 __attribute__((ext_vector_type(4)));

// ---------------------------------------------------------------------------
// Single-pass kernel with dependency-scoped flag sync (NO fences, NO cache
// invalidates — the R5-R7 killer). All cross-block data (gp means, batch
// counters) moves through cache-BYPASSING relaxed agent atomics, which go
// straight to the coherence point. Ordering:
//   writer: gp stores -> s_waitcnt vmcnt(0) -> counter RMW
//   reader: spin on counter (control dep) -> gp loads
// Pass B re-reads the block's OWN planes at re-read distance ~0 -> MALL/L2
// hot (proven by R7's FETCH=129MB), then NT-stores the output.
// ---------------------------------------------------------------------------
__global__ __launch_bounds__(256, 4) void fused_kernel(
    const float* __restrict__ x1, const float* __restrict__ x2,
    const float* __restrict__ x3, const float* __restrict__ x4,
    const float* __restrict__ conv_w, const float* __restrict__ conv_b,
    const float* __restrict__ lin_w,  const float* __restrict__ lin_b,
    float* __restrict__ gp, unsigned* __restrict__ cnt,
    float* __restrict__ out)
{
    const int tid = threadIdx.x;
    const int blk = blockIdx.x;
    const int bat = blk >> 6;                    // 64 blocks per batch
    const int c1  = (blk & 63) * PPB;            // first channel of this block
    const int pA  = bat * CHANS + c1;            // first plane index
    const int xi  = c1 >> 7;                     // 8 | 128 -> same source for all 8
    const float* src = (xi == 0) ? x1 : (xi == 1) ? x2 : (xi == 2) ? x3 : x4;
    const f32x4* p4 = (const f32x4*)(src + (size_t)(bat * 128 + (c1 & 127)) * PLANE_SZ);

    __shared__ float gwin[PPB + 64];             // gp[bat, c1-32 .. c1+PPB+31]
    __shared__ float wsum[PPB][4];
    __shared__ float gates[PPB];

    // ---- pass A: means of my 8 planes ----
    float s[PPB];
    #pragma unroll
    for (int p = 0; p < PPB; ++p) {
        f32x4 acc = p4[p * 1024 + tid];
        #pragma unroll
        for (int j = 1; j < 4; ++j)
            acc += p4[p * 1024 + j * 256 + tid];
        s[p] = (acc.x + acc.y) + (acc.z + acc.w);
    }
    #pragma unroll
    for (int off = 32; off > 0; off >>= 1)
        #pragma unroll
        for (int p = 0; p < PPB; ++p)
            s[p] += __shfl_down(s[p], off, 64);
    if ((tid & 63) == 0)
        #pragma unroll
        for (int p = 0; p < PPB; ++p)
            wsum[p][tid >> 6] = s[p];
    __syncthreads();

    // publish means (bypass atomics), then bump my batch's counter.
    // stores and RMW are all issued by wave 0 -> vmcnt orders them.
    if (tid < PPB) {
        float m = ((wsum[tid][0] + wsum[tid][1]) +
                   (wsum[tid][2] + wsum[tid][3])) * (1.0f / PLANE_SZ);
        __hip_atomic_store(&gp[pA + tid], m, __ATOMIC_RELAXED, __HIP_MEMORY_SCOPE_AGENT);
    }
    if (tid == 0) {
        asm volatile("s_waitcnt vmcnt(0)" ::: "memory");   // means visible first
        __hip_atomic_fetch_add(&cnt[bat], 1u, __ATOMIC_RELAXED, __HIP_MEMORY_SCOPE_AGENT);
        // wait for my whole batch (64 blocks) to publish
        while (__hip_atomic_load(&cnt[bat], __ATOMIC_RELAXED, __HIP_MEMORY_SCOPE_AGENT) < 64u)
            __builtin_amdgcn_s_sleep(1);
    }
    __syncthreads();
    asm volatile("" ::: "memory");

    // ---- stage gp window (bypass loads; control-dep ordered after spin) ----
    if (tid < PPB + 64) {
        int idx = c1 - 32 + tid;
        gwin[tid] = (idx >= 0 && idx < CHANS)
            ? __hip_atomic_load(&gp[bat * CHANS + idx], __ATOMIC_RELAXED, __HIP_MEMORY_SCOPE_AGENT)
            : 0.f;
    }
    __syncthreads();

    // ---- gates for channels c1..c1+7 (taps at d*(k-4), d = 1,2,4,8) ----
    if (tid < PPB) {
        float lin = lin_b[0];
        #pragma unroll
        for (int i = 0; i < 4; ++i) {
            const int d = 1 << i;
            float acc = conv_b[i];
            #pragma unroll
            for (int k = 0; k < 9; ++k)
                acc += conv_w[i * 9 + k] * gwin[32 + tid + d * (k - 4)];
            lin += lin_w[i] * fmaxf(acc, 0.f);
        }
        gates[tid] = 1.0f / (1.0f + expf(-lin));
    }
    __syncthreads();

    // ---- pass B: re-read own planes (MALL/L2-hot), scale, NT-store ----
    f32x4* o4 = (f32x4*)(out + (size_t)pA * PLANE_SZ);
    #pragma unroll
    for (int p = 0; p < PPB; ++p) {
        const float gv = gates[p];
        #pragma unroll
        for (int j = 0; j < 4; ++j) {
            f32x4 t = p4[p * 1024 + j * 256 + tid] * gv;
            __builtin_nontemporal_store(t, &o4[p * 1024 + j * 256 + tid]);
        }
    }
}

extern "C" void kernel_launch(void* const* d_in, const int* in_sizes, int n_in,
                              void* d_out, int out_size, void* d_ws, size_t ws_size,
                              hipStream_t stream) {
    const float* x1     = (const float*)d_in[0];
    const float* x2     = (const float*)d_in[1];
    const float* x3     = (const float*)d_in[2];
    const float* x4     = (const float*)d_in[3];
    const float* conv_w = (const float*)d_in[4];
    const float* conv_b = (const float*)d_in[5];
    const float* lin_w  = (const float*)d_in[6];
    const float* lin_b  = (const float*)d_in[7];
    float* out = (float*)d_out;

    float*    gp  = (float*)d_ws;                          // PLANES floats
    unsigned* cnt = (unsigned*)((char*)d_ws + PLANES * sizeof(float));

    // per-batch counters must be zero at the start of EVERY call (ws poisoned,
    // and left at 64 by the previous call)
    hipMemsetAsync(cnt, 0, NBATCH * sizeof(unsigned), stream);

    fused_kernel<<<NBLK, 256, 0, stream>>>(x1, x2, x3, x4,
                                           conv_w, conv_b, lin_w, lin_b,
                                           gp, cnt, out);
}

// Round 10
// 67.968 us; speedup vs baseline: 1.6746x; 1.6746x over previous
//
#include <hip/hip_runtime.h>
#include <math.h>

#define PLANES   8192   // 16 batches * 512 channels
#define PLANE_SZ 4096   // 64*64
#define CHANS    512
#define NBLK     1024   // 4 blocks/CU * 256 CUs -> co-resident (proven R5-R9)
#define PPB      8      // planes (channels) per block; 64 blocks per batch

typedef float f32x4 __attribute__((ext_vector_type(4)));

// ---------------------------------------------------------------------------
// Single-pass kernel, NEIGHBOR-scoped flag sync (R9 fix).
// R9 proved: traffic is ideal (input fetched once, pass-B re-read MALL-hot),
// but a batch-wide barrier with fast spins saturates the coherence point.
// The gate for channels c1..c1+7 needs means c1-32..c1+39 = blocks lb-4..lb+4
// only. So: per-block cacheline-padded done-flags; each block polls just its
// <=9 neighbors. Publication pattern (gp stores -> vmcnt(0) -> flag store,
// readers: flag poll -> control dep -> cache-bypass gp loads) proven in R9.
// ---------------------------------------------------------------------------
__global__ __launch_bounds__(256, 4) void fused_kernel(
    const float* __restrict__ x1, const float* __restrict__ x2,
    const float* __restrict__ x3, const float* __restrict__ x4,
    const float* __restrict__ conv_w, const float* __restrict__ conv_b,
    const float* __restrict__ lin_w,  const float* __restrict__ lin_b,
    float* __restrict__ gp, unsigned* __restrict__ flags,
    float* __restrict__ out)
{
    const int tid = threadIdx.x;
    const int blk = blockIdx.x;
    const int bat = blk >> 6;                    // 64 blocks per batch
    const int lb  = blk & 63;                    // local block in batch
    const int c1  = lb * PPB;                    // first channel of this block
    const int pA  = bat * CHANS + c1;            // first plane index
    const int xi  = c1 >> 7;                     // 8 | 128 -> same source for all 8
    const float* src = (xi == 0) ? x1 : (xi == 1) ? x2 : (xi == 2) ? x3 : x4;
    const f32x4* p4 = (const f32x4*)(src + (size_t)(bat * 128 + (c1 & 127)) * PLANE_SZ);

    __shared__ float gwin[PPB + 64];             // gp[bat, c1-32 .. c1+PPB+31]
    __shared__ float wsum[PPB][4];
    __shared__ float gates[PPB];

    // ---- pass A: means of my 8 planes ----
    float s[PPB];
    #pragma unroll
    for (int p = 0; p < PPB; ++p) {
        f32x4 acc = p4[p * 1024 + tid];
        #pragma unroll
        for (int j = 1; j < 4; ++j)
            acc += p4[p * 1024 + j * 256 + tid];
        s[p] = (acc.x + acc.y) + (acc.z + acc.w);
    }
    #pragma unroll
    for (int off = 32; off > 0; off >>= 1)
        #pragma unroll
        for (int p = 0; p < PPB; ++p)
            s[p] += __shfl_down(s[p], off, 64);
    if ((tid & 63) == 0)
        #pragma unroll
        for (int p = 0; p < PPB; ++p)
            wsum[p][tid >> 6] = s[p];
    __syncthreads();

    // publish my 8 means (cache-bypass stores), then set my done-flag.
    // All issued by wave 0 -> the vmcnt wait orders stores before the flag.
    if (tid < PPB) {
        float m = ((wsum[tid][0] + wsum[tid][1]) +
                   (wsum[tid][2] + wsum[tid][3])) * (1.0f / PLANE_SZ);
        __hip_atomic_store(&gp[pA + tid], m, __ATOMIC_RELAXED, __HIP_MEMORY_SCOPE_AGENT);
    }
    if (tid == 0) {
        asm volatile("s_waitcnt vmcnt(0)" ::: "memory");   // means visible first
        __hip_atomic_store(&flags[blk * 16], 1u, __ATOMIC_RELAXED, __HIP_MEMORY_SCOPE_AGENT);
        // wait only for my window's neighbors (<=9 blocks, incl. self)
        const int lo = (lb - 4 < 0) ? 0 : lb - 4;
        const int hi = (lb + 4 > 63) ? 63 : lb + 4;
        for (int nb = lo; nb <= hi; ++nb) {
            const unsigned* f = &flags[(bat * 64 + nb) * 16];
            while (__hip_atomic_load(f, __ATOMIC_RELAXED, __HIP_MEMORY_SCOPE_AGENT) == 0u)
                __builtin_amdgcn_s_sleep(8);
        }
    }
    __syncthreads();
    asm volatile("" ::: "memory");

    // ---- stage gp window (cache-bypass loads; ordered by flag control dep) ----
    if (tid < PPB + 64) {
        int idx = c1 - 32 + tid;
        gwin[tid] = (idx >= 0 && idx < CHANS)
            ? __hip_atomic_load(&gp[bat * CHANS + idx], __ATOMIC_RELAXED, __HIP_MEMORY_SCOPE_AGENT)
            : 0.f;
    }
    __syncthreads();

    // ---- gates for channels c1..c1+7 (taps at d*(k-4), d = 1,2,4,8) ----
    if (tid < PPB) {
        float lin = lin_b[0];
        #pragma unroll
        for (int i = 0; i < 4; ++i) {
            const int d = 1 << i;
            float acc = conv_b[i];
            #pragma unroll
            for (int k = 0; k < 9; ++k)
                acc += conv_w[i * 9 + k] * gwin[32 + tid + d * (k - 4)];
            lin += lin_w[i] * fmaxf(acc, 0.f);
        }
        gates[tid] = 1.0f / (1.0f + expf(-lin));
    }
    __syncthreads();

    // ---- pass B: re-read own planes (MALL-hot), scale, NT-store ----
    f32x4* o4 = (f32x4*)(out + (size_t)pA * PLANE_SZ);
    #pragma unroll
    for (int p = 0; p < PPB; ++p) {
        const float gv = gates[p];
        #pragma unroll
        for (int j = 0; j < 4; ++j) {
            f32x4 t = p4[p * 1024 + j * 256 + tid] * gv;
            __builtin_nontemporal_store(t, &o4[p * 1024 + j * 256 + tid]);
        }
    }
}

extern "C" void kernel_launch(void* const* d_in, const int* in_sizes, int n_in,
                              void* d_out, int out_size, void* d_ws, size_t ws_size,
                              hipStream_t stream) {
    const float* x1     = (const float*)d_in[0];
    const float* x2     = (const float*)d_in[1];
    const float* x3     = (const float*)d_in[2];
    const float* x4     = (const float*)d_in[3];
    const float* conv_w = (const float*)d_in[4];
    const float* conv_b = (const float*)d_in[5];
    const float* lin_w  = (const float*)d_in[6];
    const float* lin_b  = (const float*)d_in[7];
    float* out = (float*)d_out;

    float*    gp    = (float*)d_ws;                          // PLANES floats
    unsigned* flags = (unsigned*)((char*)d_ws + PLANES * sizeof(float));

    // flags (1024 x 64B) must be zero at the start of EVERY call
    hipMemsetAsync(flags, 0, NBLK * 16 * sizeof(unsigned), stream);

    fused_kernel<<<NBLK, 256, 0, stream>>>(x1, x2, x3, x4,
                                           conv_w, conv_b, lin_w, lin_b,
                                           gp, flags, out);
}

// Round 11
// 56.860 us; speedup vs baseline: 2.0018x; 1.1954x over previous
//
#include <hip/hip_runtime.h>
#include <math.h>

#define PLANES   8192   // 16 batches * 512 channels
#define PLANE_SZ 4096   // 64*64
#define CHANS    512
#define NBLK     2048   // 512 resident (2/CU); rest pipeline in
#define PPB      4      // planes (channels) per block; 128 blocks per batch

typedef float f32x4 __attribute__((ext_vector_type(4)));

// ---------------------------------------------------------------------------
// Single-pass, data retained in REGISTERS across the sync (no re-read at all).
//  - R5 failed: no pin -> compiler sank the loads past the sync (re-loaded).
//  - R6 failed: pin at launch_bounds(256,4) -> 128-VGPR cap -> scratch spill.
//  - Fix: PPB=4 (64 data VGPRs) + __launch_bounds__(256,2) (256-VGPR cap)
//    + asm pin AFTER the mean consumes every value.
//  - Sync: R10's proven neighbor-scoped flags, window +-8 blocks (= channels
//    c1-32..c1+35). Non-co-resident 2048-block pipeline is deadlock-free:
//    waits only reach 8 blocks forward.
// HBM traffic: input read once (134 MB) + output written once (134 MB). No
// MALL re-read (the R10 cost).
// ---------------------------------------------------------------------------
__global__ __launch_bounds__(256, 2) void fused_kernel(
    const float* __restrict__ x1, const float* __restrict__ x2,
    const float* __restrict__ x3, const float* __restrict__ x4,
    const float* __restrict__ conv_w, const float* __restrict__ conv_b,
    const float* __restrict__ lin_w,  const float* __restrict__ lin_b,
    float* __restrict__ gp, unsigned* __restrict__ flags,
    float* __restrict__ out)
{
    const int tid = threadIdx.x;
    const int blk = blockIdx.x;
    const int bat = blk >> 7;                    // 128 blocks per batch
    const int lb  = blk & 127;                   // local block in batch
    const int c1  = lb * PPB;                    // first channel of this block
    const int pA  = bat * CHANS + c1;            // first plane index
    const int xi  = c1 >> 7;                     // 4 | 128 -> same source for all 4
    const float* src = (xi == 0) ? x1 : (xi == 1) ? x2 : (xi == 2) ? x3 : x4;
    const f32x4* p4 = (const f32x4*)(src + (size_t)(bat * 128 + (c1 & 127)) * PLANE_SZ);

    __shared__ float gwin[PPB + 64];             // gp[bat, c1-32 .. c1+PPB+31]
    __shared__ float wsum[PPB][4];
    __shared__ float gates[PPB];

    // ---- pass A: load 4 planes into registers, compute means ----
    f32x4 v[PPB][4];
    #pragma unroll
    for (int p = 0; p < PPB; ++p)
        #pragma unroll
        for (int j = 0; j < 4; ++j)
            v[p][j] = p4[p * 1024 + j * 256 + tid];

    float s[PPB];
    #pragma unroll
    for (int p = 0; p < PPB; ++p) {
        f32x4 t = (v[p][0] + v[p][1]) + (v[p][2] + v[p][3]);
        s[p] = (t.x + t.y) + (t.z + t.w);
    }
    #pragma unroll
    for (int off = 32; off > 0; off >>= 1)
        #pragma unroll
        for (int p = 0; p < PPB; ++p)
            s[p] += __shfl_down(s[p], off, 64);
    if ((tid & 63) == 0)
        #pragma unroll
        for (int p = 0; p < PPB; ++p)
            wsum[p][tid >> 6] = s[p];
    __syncthreads();

    // publish my 4 means (cache-bypass stores), then set my done-flag
    if (tid < PPB) {
        float m = ((wsum[tid][0] + wsum[tid][1]) +
                   (wsum[tid][2] + wsum[tid][3])) * (1.0f / PLANE_SZ);
        __hip_atomic_store(&gp[pA + tid], m, __ATOMIC_RELAXED, __HIP_MEMORY_SCOPE_AGENT);
    }

    // PIN: every v was consumed by the mean (loads complete); make them
    // opaque so the compiler can neither sink nor re-materialize the loads.
    #pragma unroll
    for (int p = 0; p < PPB; ++p)
        #pragma unroll
        for (int j = 0; j < 4; ++j)
            asm volatile("" : "+v"(v[p][j]));

    if (tid == 0) {
        asm volatile("s_waitcnt vmcnt(0)" ::: "memory");   // means visible first
        __hip_atomic_store(&flags[blk * 16], 1u, __ATOMIC_RELAXED, __HIP_MEMORY_SCOPE_AGENT);
        // wait for my gate window's producers: blocks lb-8 .. lb+8
        const int lo = (lb - 8 < 0) ? 0 : lb - 8;
        const int hi = (lb + 8 > 127) ? 127 : lb + 8;
        for (int nb = lo; nb <= hi; ++nb) {
            const unsigned* f = &flags[((bat << 7) + nb) * 16];
            while (__hip_atomic_load(f, __ATOMIC_RELAXED, __HIP_MEMORY_SCOPE_AGENT) == 0u)
                __builtin_amdgcn_s_sleep(8);
        }
    }
    __syncthreads();
    asm volatile("" ::: "memory");

    // ---- stage gp window (cache-bypass loads, ordered by flag control dep) ----
    if (tid < PPB + 64) {
        int idx = c1 - 32 + tid;
        gwin[tid] = (idx >= 0 && idx < CHANS)
            ? __hip_atomic_load(&gp[bat * CHANS + idx], __ATOMIC_RELAXED, __HIP_MEMORY_SCOPE_AGENT)
            : 0.f;
    }
    __syncthreads();

    // ---- gates for channels c1..c1+3 (taps at d*(k-4), d = 1,2,4,8) ----
    if (tid < PPB) {
        float lin = lin_b[0];
        #pragma unroll
        for (int i = 0; i < 4; ++i) {
            const int d = 1 << i;
            float acc = conv_b[i];
            #pragma unroll
            for (int k = 0; k < 9; ++k)
                acc += conv_w[i * 9 + k] * gwin[32 + tid + d * (k - 4)];
            lin += lin_w[i] * fmaxf(acc, 0.f);
        }
        gates[tid] = 1.0f / (1.0f + expf(-lin));
    }
    __syncthreads();

    // ---- pass B: scale the RETAINED registers, NT-store (no re-read) ----
    f32x4* o4 = (f32x4*)(out + (size_t)pA * PLANE_SZ);
    #pragma unroll
    for (int p = 0; p < PPB; ++p) {
        const float gv = gates[p];
        #pragma unroll
        for (int j = 0; j < 4; ++j) {
            f32x4 t = v[p][j] * gv;
            __builtin_nontemporal_store(t, &o4[p * 1024 + j * 256 + tid]);
        }
    }
}

extern "C" void kernel_launch(void* const* d_in, const int* in_sizes, int n_in,
                              void* d_out, int out_size, void* d_ws, size_t ws_size,
                              hipStream_t stream) {
    const float* x1     = (const float*)d_in[0];
    const float* x2     = (const float*)d_in[1];
    const float* x3     = (const float*)d_in[2];
    const float* x4     = (const float*)d_in[3];
    const float* conv_w = (const float*)d_in[4];
    const float* conv_b = (const float*)d_in[5];
    const float* lin_w  = (const float*)d_in[6];
    const float* lin_b  = (const float*)d_in[7];
    float* out = (float*)d_out;

    float*    gp    = (float*)d_ws;                          // PLANES floats
    unsigned* flags = (unsigned*)((char*)d_ws + PLANES * sizeof(float));

    // flags (2048 x 64B) must be zero at the start of EVERY call
    hipMemsetAsync(flags, 0, NBLK * 16 * sizeof(unsigned), stream);

    fused_kernel<<<NBLK, 256, 0, stream>>>(x1, x2, x3, x4,
                                           conv_w, conv_b, lin_w, lin_b,
                                           gp, flags, out);
}

// Round 12
// 56.756 us; speedup vs baseline: 2.0055x; 1.0018x over previous
//
#include <hip/hip_runtime.h>
#include <math.h>

#define PLANES   8192   // 16 batches * 512 channels
#define PLANE_SZ 4096   // 64*64
#define CHANS    512
#define NBLK     4096   // 4/CU resident (launch_bounds 256,4); pipeline the rest
#define PPB      2      // planes (channels) per block; 256 blocks per batch

typedef float f32x4 __attribute__((ext_vector_type(4)));

// ---------------------------------------------------------------------------
// Single-pass, registers retained across neighbor-scoped flag sync (R11 win,
// 56.9us). Changes vs R11:
//  - PPB 4->2 + launch_bounds(256,4): 16 waves/CU (was 8) for latency hiding;
//    32 data VGPRs fit the 128-cap (compiler stashes to AGPRs per R11).
//  - lane-parallel flag poll (<=33 lanes, one flag each): wait = max, not sum.
//  - NT input loads: lines are consumed exactly once into registers; skipping
//    allocation stops the input stream churning MALL against the NT writes.
// HBM traffic: input read once (134 MB) + output written once (134 MB).
// ---------------------------------------------------------------------------
__global__ __launch_bounds__(256, 4) void fused_kernel(
    const float* __restrict__ x1, const float* __restrict__ x2,
    const float* __restrict__ x3, const float* __restrict__ x4,
    const float* __restrict__ conv_w, const float* __restrict__ conv_b,
    const float* __restrict__ lin_w,  const float* __restrict__ lin_b,
    float* __restrict__ gp, unsigned* __restrict__ flags,
    float* __restrict__ out)
{
    const int tid = threadIdx.x;
    const int blk = blockIdx.x;
    const int bat = blk >> 8;                    // 256 blocks per batch
    const int lb  = blk & 255;                   // local block in batch
    const int c1  = lb * PPB;                    // first channel of this block
    const int pA  = bat * CHANS + c1;            // first plane index
    const int xi  = c1 >> 7;                     // 2 | 128 -> same source for both
    const float* src = (xi == 0) ? x1 : (xi == 1) ? x2 : (xi == 2) ? x3 : x4;
    const f32x4* p4 = (const f32x4*)(src + (size_t)(bat * 128 + (c1 & 127)) * PLANE_SZ);

    __shared__ float gwin[PPB + 64];             // gp[bat, c1-32 .. c1+PPB+31]
    __shared__ float wsum[PPB][4];
    __shared__ float gates[PPB];

    // ---- pass A: load 2 planes into registers (NT), compute means ----
    f32x4 v[PPB][4];
    #pragma unroll
    for (int p = 0; p < PPB; ++p)
        #pragma unroll
        for (int j = 0; j < 4; ++j)
            v[p][j] = __builtin_nontemporal_load(&p4[p * 1024 + j * 256 + tid]);

    float s[PPB];
    #pragma unroll
    for (int p = 0; p < PPB; ++p) {
        f32x4 t = (v[p][0] + v[p][1]) + (v[p][2] + v[p][3]);
        s[p] = (t.x + t.y) + (t.z + t.w);
    }
    #pragma unroll
    for (int off = 32; off > 0; off >>= 1)
        #pragma unroll
        for (int p = 0; p < PPB; ++p)
            s[p] += __shfl_down(s[p], off, 64);
    if ((tid & 63) == 0)
        #pragma unroll
        for (int p = 0; p < PPB; ++p)
            wsum[p][tid >> 6] = s[p];
    __syncthreads();

    // publish my 2 means (cache-bypass stores), then set my done-flag
    if (tid < PPB) {
        float m = ((wsum[tid][0] + wsum[tid][1]) +
                   (wsum[tid][2] + wsum[tid][3])) * (1.0f / PLANE_SZ);
        __hip_atomic_store(&gp[pA + tid], m, __ATOMIC_RELAXED, __HIP_MEMORY_SCOPE_AGENT);
    }

    // PIN retained data (R11-proven: lands in AGPRs, no spill)
    #pragma unroll
    for (int p = 0; p < PPB; ++p)
        #pragma unroll
        for (int j = 0; j < 4; ++j)
            asm volatile("" : "+v"(v[p][j]));

    if (tid == 0) {
        asm volatile("s_waitcnt vmcnt(0)" ::: "memory");   // means visible first
        __hip_atomic_store(&flags[blk * 16], 1u, __ATOMIC_RELAXED, __HIP_MEMORY_SCOPE_AGENT);
    }
    __syncthreads();   // flag set before anyone proceeds to poll

    // lane-parallel wait for the gate window's producers: blocks lb-16..lb+16
    {
        const int lo = (lb - 16 < 0) ? 0 : lb - 16;
        const int hi = (lb + 16 > 255) ? 255 : lb + 16;
        const int nf = hi - lo + 1;              // <= 33
        if (tid < nf) {
            const unsigned* f = &flags[((bat << 8) + lo + tid) * 16];
            while (__hip_atomic_load(f, __ATOMIC_RELAXED, __HIP_MEMORY_SCOPE_AGENT) == 0u)
                __builtin_amdgcn_s_sleep(8);
        }
    }
    __syncthreads();
    asm volatile("" ::: "memory");

    // ---- stage gp window (cache-bypass loads, ordered by flag control dep) ----
    if (tid < PPB + 64) {
        int idx = c1 - 32 + tid;
        gwin[tid] = (idx >= 0 && idx < CHANS)
            ? __hip_atomic_load(&gp[bat * CHANS + idx], __ATOMIC_RELAXED, __HIP_MEMORY_SCOPE_AGENT)
            : 0.f;
    }
    __syncthreads();

    // ---- gates for channels c1..c1+1 (taps at d*(k-4), d = 1,2,4,8) ----
    if (tid < PPB) {
        float lin = lin_b[0];
        #pragma unroll
        for (int i = 0; i < 4; ++i) {
            const int d = 1 << i;
            float acc = conv_b[i];
            #pragma unroll
            for (int k = 0; k < 9; ++k)
                acc += conv_w[i * 9 + k] * gwin[32 + tid + d * (k - 4)];
            lin += lin_w[i] * fmaxf(acc, 0.f);
        }
        gates[tid] = 1.0f / (1.0f + expf(-lin));
    }
    __syncthreads();

    // ---- pass B: scale the RETAINED registers, NT-store (no re-read) ----
    f32x4* o4 = (f32x4*)(out + (size_t)pA * PLANE_SZ);
    #pragma unroll
    for (int p = 0; p < PPB; ++p) {
        const float gv = gates[p];
        #pragma unroll
        for (int j = 0; j < 4; ++j) {
            f32x4 t = v[p][j] * gv;
            __builtin_nontemporal_store(t, &o4[p * 1024 + j * 256 + tid]);
        }
    }
}

extern "C" void kernel_launch(void* const* d_in, const int* in_sizes, int n_in,
                              void* d_out, int out_size, void* d_ws, size_t ws_size,
                              hipStream_t stream) {
    const float* x1     = (const float*)d_in[0];
    const float* x2     = (const float*)d_in[1];
    const float* x3     = (const float*)d_in[2];
    const float* x4     = (const float*)d_in[3];
    const float* conv_w = (const float*)d_in[4];
    const float* conv_b = (const float*)d_in[5];
    const float* lin_w  = (const float*)d_in[6];
    const float* lin_b  = (const float*)d_in[7];
    float* out = (float*)d_out;

    float*    gp    = (float*)d_ws;                          // PLANES floats
    unsigned* flags = (unsigned*)((char*)d_ws + PLANES * sizeof(float));

    // flags (4096 x 64B) must be zero at the start of EVERY call
    hipMemsetAsync(flags, 0, NBLK * 16 * sizeof(unsigned), stream);

    fused_kernel<<<NBLK, 256, 0, stream>>>(x1, x2, x3, x4,
                                           conv_w, conv_b, lin_w, lin_b,
                                           gp, flags, out);
}